// Round 17
// baseline (324.809 us; speedup 1.0000x reference)
//
#include <hip/hip_runtime.h>
#include <hip/hip_bf16.h>

typedef __attribute__((ext_vector_type(8))) short short8;     // 8 bf16 (4 VGPRs) MFMA A/B frag
typedef __attribute__((ext_vector_type(4))) float f32x4;      // 16x16 MFMA C/D frag
typedef __attribute__((ext_vector_type(16))) float f32x16;    // 32x32 MFMA C/D frag
typedef __attribute__((ext_vector_type(4))) unsigned short u16x4;
typedef __attribute__((ext_vector_type(8))) unsigned short u16x8;
typedef __attribute__((ext_vector_type(4))) unsigned int u32x4;

#define MFMA16(a, b, c) __builtin_amdgcn_mfma_f32_16x16x32_bf16((a), (b), (c), 0, 0, 0)
#define MFMA32(a, b, c) __builtin_amdgcn_mfma_f32_32x32x16_bf16((a), (b), (c), 0, 0, 0)

__device__ __forceinline__ unsigned short f2bf(float f) {
    union { float f; unsigned u; } v; v.f = f;
    return (unsigned short)((v.u + 0x7fffu + ((v.u >> 16) & 1u)) >> 16);
}

__device__ __forceinline__ float bf2f(unsigned short s) {
    union { unsigned u; float f; } v; v.u = (unsigned)s << 16;
    return v.f;
}

__device__ __forceinline__ unsigned cvtpk(float lo, float hi_) {
    unsigned r;
    asm volatile("v_cvt_pk_bf16_f32 %0, %1, %2" : "=v"(r) : "v"(lo), "v"(hi_));
    return r;
}

// ---------------------------------------------------------------- fused prep
// blocks [0,4096): cast X f32 -> bf16 (one float4/thread)
// blocks [4096,4864): transpose+cast Wqkv [1024][3072] -> WqkvT [3072][1024]
// blocks [4864,5120): transpose+cast Wproj [1024][1024] -> WprojT [1024][1024]
__global__ __launch_bounds__(256)
void prep_kernel(const float* __restrict__ X, ushort* __restrict__ Xb,
                 const float* __restrict__ Wqkv, ushort* __restrict__ WqkvT,
                 const float* __restrict__ Wproj, ushort* __restrict__ WprojT) {
    __shared__ ushort t[64][66];                        // transpose tile (66: conflict-free)
    const int b = blockIdx.x;
    const int tid = threadIdx.x;
    if (b < 4096) {
        int i = b * 256 + tid;
        float4 v = ((const float4*)X)[i];
        u16x4 o = { f2bf(v.x), f2bf(v.y), f2bf(v.z), f2bf(v.w) };
        *(u16x4*)(Xb + (size_t)i * 4) = o;
        return;
    }
    const float* W; ushort* WT; int N, idx;
    if (b < 4864) { W = Wqkv;  WT = WqkvT;  N = 3072; idx = b - 4096; }
    else          { W = Wproj; WT = WprojT; N = 1024; idx = b - 4864; }
    const int nblk = N >> 6;
    const int n0 = (idx % nblk) * 64, k0 = (idx / nblk) * 64;
    const int tn = tid & 63, tg = tid >> 6;
#pragma unroll
    for (int i = 0; i < 16; ++i) {
        int k = tg * 16 + i;
        t[tn][k] = f2bf(W[(size_t)(k0 + k) * N + n0 + tn]);
    }
    __syncthreads();
#pragma unroll
    for (int i = 0; i < 16; ++i) {
        int nn = tg * 16 + i;
        WT[(size_t)(n0 + nn) * 1024 + k0 + tn] = t[nn][tn];
    }
}

// ---------------------------------------------------------------- GEMM C = A @ BT^T
// (unchanged from round 16 — T4 counted-vmcnt 3-buffer, BK=32, slot swizzle.)
#define QSCALE 0.18033688011112042f   /* 0.125 * log2(e) */

template <int MODE>
__global__ __launch_bounds__(256, 3)
void gemm_bt_kernel(const ushort* __restrict__ A, const ushort* __restrict__ BT,
                    const float* __restrict__ bias,
                    ushort* __restrict__ Qb, ushort* __restrict__ Kb,
                    ushort* __restrict__ VT, float* __restrict__ Out,
                    int M, int N, int K) {
    __shared__ ushort Asm[3][128 * 32];                 // [row][32], 16B-slot swizzled
    __shared__ ushort Bsm[3][128 * 32];
    const int tid = threadIdx.x;
    const int lane = tid & 63;
    const int wv = tid >> 6;
    const int l15 = lane & 15, lg = lane >> 4;
    const int rm = (wv >> 1) * 64, cn = (wv & 1) * 64;  // wave's 64x64 sub-tile
    const int row0 = blockIdx.y * 128, col0 = blockIdx.x * 128;

    const char* Agb = (const char*)(A + (size_t)row0 * K);
    const char* Bgb = (const char*)(BT + (size_t)col0 * K);
    const size_t rowbytes = (size_t)K * 2;

    f32x4 acc[4][4];
#pragma unroll
    for (int mi = 0; mi < 4; ++mi)
#pragma unroll
        for (int ni = 0; ni < 4; ++ni) acc[mi][ni] = f32x4{0.f, 0.f, 0.f, 0.f};

    // staging: 512 slots (128 rows x 4 x16B), 2 per thread; source col swizzled.
    const int sr0 = tid >> 2, sc0 = (tid & 3) ^ (sr0 & 3);          // slot tid
    const int sr1 = (tid + 256) >> 2, sc1 = (tid & 3) ^ (sr1 & 3);  // slot tid+256

#define GSTAGE(buf, k0_)                                                                \
    do {                                                                                \
        size_t kbyte = (size_t)(k0_)*2;                                                 \
        __builtin_amdgcn_global_load_lds(                                               \
            (const __attribute__((address_space(1))) void*)(Agb + (size_t)sr0 *         \
                rowbytes + kbyte + sc0 * 16),                                           \
            (__attribute__((address_space(3))) void*)((char*)&Asm[buf][0] + tid * 16),  \
            16, 0, 0);                                                                  \
        __builtin_amdgcn_global_load_lds(                                               \
            (const __attribute__((address_space(1))) void*)(Agb + (size_t)sr1 *         \
                rowbytes + kbyte + sc1 * 16),                                           \
            (__attribute__((address_space(3))) void*)((char*)&Asm[buf][0] + 4096 +      \
                tid * 16),                                                              \
            16, 0, 0);                                                                  \
        __builtin_amdgcn_global_load_lds(                                               \
            (const __attribute__((address_space(1))) void*)(Bgb + (size_t)sr0 *         \
                rowbytes + kbyte + sc0 * 16),                                           \
            (__attribute__((address_space(3))) void*)((char*)&Bsm[buf][0] + tid * 16),  \
            16, 0, 0);                                                                  \
        __builtin_amdgcn_global_load_lds(                                               \
            (const __attribute__((address_space(1))) void*)(Bgb + (size_t)sr1 *         \
                rowbytes + kbyte + sc1 * 16),                                           \
            (__attribute__((address_space(3))) void*)((char*)&Bsm[buf][0] + 4096 +      \
                tid * 16),                                                              \
            16, 0, 0);                                                                  \
    } while (0)

    const int NK = K >> 5;                               // 32-wide k-steps (K=1024 -> 32)
    GSTAGE(0, 0);
    GSTAGE(1, 32);

    // read swizzle: row R, elems lg*8..+7 live at slot lg^(R&3); R&3 == l15&3.
    const int sw8 = (lg ^ (l15 & 3)) << 3;

    int cur = 0, stg = 2;
    for (int i = 0; i < NK; ++i) {
        if (i < NK - 1) asm volatile("s_waitcnt vmcnt(4)" ::: "memory");
        else            asm volatile("s_waitcnt vmcnt(0)" ::: "memory");
        __builtin_amdgcn_s_barrier();                    // batch i visible; i+1 in flight
        if (i + 2 < NK) GSTAGE(stg, (i + 2) * 32);
        short8 af[4], bf[4];
#pragma unroll
        for (int mi = 0; mi < 4; ++mi)
            af[mi] = *(const short8*)&Asm[cur][(rm + mi * 16 + l15) * 32 + sw8];
#pragma unroll
        for (int ni = 0; ni < 4; ++ni)
            bf[ni] = *(const short8*)&Bsm[cur][(cn + ni * 16 + l15) * 32 + sw8];
        __builtin_amdgcn_s_setprio(1);
#pragma unroll
        for (int mi = 0; mi < 4; ++mi)
#pragma unroll
            for (int ni = 0; ni < 4; ++ni)
                acc[mi][ni] = MFMA16(af[mi], bf[ni], acc[mi][ni]);
        __builtin_amdgcn_s_setprio(0);
        cur = (cur == 2) ? 0 : cur + 1;
        stg = (stg == 2) ? 0 : stg + 1;
    }
#undef GSTAGE

    // Epilogue. D layout: lane holds D[(lg)*4+j][l15] (row=M dim, col=N dim).
    if (MODE == 0) {
        const int sect = col0 >> 10;   // 0=q 1=k 2=v, uniform per block (128 | 1024)
#pragma unroll
        for (int ni = 0; ni < 4; ++ni) {
            int col = col0 + cn + ni * 16 + l15;
            float bv = bias[col];
            int dcol = col & 1023, h = dcol >> 6, dd = dcol & 63;
#pragma unroll
            for (int mi = 0; mi < 4; ++mi) {
                int mrow0 = row0 + rm + mi * 16 + lg * 4;
                if (sect == 2) {
                    int b = mrow0 >> 11, s = mrow0 & 2047;   // 4 consecutive s, same b
                    u16x4 o;
#pragma unroll
                    for (int j = 0; j < 4; ++j) o[j] = f2bf(acc[mi][ni][j] + bv);
                    *(u16x4*)&VT[((size_t)((b << 4) + h) * 64 + dd) * 2048 + s] = o;
                } else {
                    ushort* dst = sect ? Kb : Qb;
                    float sc = sect ? 1.f : QSCALE;
#pragma unroll
                    for (int j = 0; j < 4; ++j) {
                        int tok = mrow0 + j;
                        int b = tok >> 11, s = tok & 2047;
                        dst[((size_t)((b << 4) + h) * 2048 + s) * 64 + dd] =
                            f2bf((acc[mi][ni][j] + bv) * sc);
                    }
                }
            }
        }
    } else {
#pragma unroll
        for (int ni = 0; ni < 4; ++ni) {
            int col = col0 + cn + ni * 16 + l15;
            float bv = bias[col];
#pragma unroll
            for (int mi = 0; mi < 4; ++mi) {
                int mrow0 = row0 + rm + mi * 16 + lg * 4;
#pragma unroll
                for (int j = 0; j < 4; ++j)
                    Out[(size_t)(mrow0 + j) * N + col] = acc[mi][ni][j] + bv;
            }
        }
    }
}

// ---------------------------------------------------------------- causal flash attention v13
// = v12 (round 16, 46us, verified) + FUSED MERGE via atomic handshake:
// both halves write bf16 OP + fp32 ML (as before), __threadfence(), then one
// atomicAdd(FLAG[bid],1)/block; the SECOND arriver (old==1, acc still in regs)
// fences, reads only the OTHER half's partials, and writes normalized CTX.
// Deterministic: merge formula symmetric in halves (M = max(m_w,m_l)).
// Device-scope atomic + threadfence covers cross-XCD visibility (G12/G16).
// FLAG zeroed per launch via hipMemsetAsync.
template <int SPLIT>
__global__ __launch_bounds__(256, 4)
void attn_kernel(const ushort* __restrict__ Qb, const ushort* __restrict__ Kb,
                 const ushort* __restrict__ VT, ushort* __restrict__ CTX,
                 ushort* __restrict__ OP, float* __restrict__ ML,
                 int* __restrict__ FLAG) {
    __shared__ __align__(16) ushort Ksm[2][64 * 64];    // [key][d], 16B-slot XOR-swizzled
    __shared__ __align__(16) ushort Vsm[2][64 * 64];    // [d][key], 16B-slot XOR-swizzled
    __shared__ int sOld;

    const int tid = threadIdx.x;
    const int lane = tid & 63;
    const int w = tid >> 6;
    const int l31 = lane & 31;
    const int hi = lane >> 5;                            // 0/1
    const int r7 = l31 & 7;

    const int id = blockIdx.x;
    int bh, qt, half, cBeg, cEnd;
    if (SPLIT) {
        const int xcd = id & 7, jj = id >> 3;            // jj 0..127
        bh = (xcd << 2) + (jj & 3);                      // 4 heads per XCD
        const int r = jj >> 2;                           // 0..31
        half = r >> 4;
        const int s = r & 15;
        qt = (s < 8) ? s : 23 - s;                       // orbit {r,r+8,+16,+24} -> (qt,15-qt)x2h
        cBeg = half * (qt + 1);
        cEnd = cBeg + (qt + 1);
    } else {
        const int xcd = id & 7, jj = id >> 3;
        bh = (xcd << 2) + (jj >> 4);
        qt = ((jj >> 5) & 1) ? (jj & 15) : 15 - (jj & 15);
        half = 0; cBeg = 0; cEnd = 2 * qt + 2;
    }
    const int nc = 2 * qt + 2;
    const int qw0 = qt * 128 + w * 32;                   // wave's 32 q-rows
    const int qrow = qw0 + l31;

    const ushort* Qh = Qb + (size_t)bh * 2048 * 64;
    const ushort* Kh = Kb + (size_t)bh * 2048 * 64;
    const ushort* Vh = VT + (size_t)bh * 64 * 2048;

    // Q fragments: B-operand of QK mfma: lane needs Q[qrow][dc*16+hi*8..+7]
    short8 qf[4];
#pragma unroll
    for (int dc = 0; dc < 4; ++dc)
        qf[dc] = *(const short8*)&Qh[(size_t)qrow * 64 + dc * 16 + hi * 8];

    // staging geometry (round-4-verified): LDS dest linear, global SOURCE swizzled.
    const int srow = tid >> 3;                           // 0..31
    const int sxor = ((tid & 7) ^ (srow & 7)) * 8;       // swizzled source col (elems)

#define GLL(src, dst) __builtin_amdgcn_global_load_lds(                                 \
        (const __attribute__((address_space(1))) void*)(src),                           \
        (__attribute__((address_space(3))) void*)(dst), 16, 0, 0)

#define STAGE(buf, kb_)                                                                 \
    do {                                                                                \
        const ushort* kp = Kh + (size_t)((kb_) + srow) * 64 + sxor;                     \
        GLL(kp, (char*)&Ksm[buf][0] + tid * 16);                                        \
        GLL(kp + 32 * 64, (char*)&Ksm[buf][0] + 4096 + tid * 16);                       \
        const ushort* vp = Vh + (size_t)srow * 2048 + (kb_) + sxor;                     \
        GLL(vp, (char*)&Vsm[buf][0] + tid * 16);                                        \
        GLL(vp + (size_t)32 * 2048, (char*)&Vsm[buf][0] + 4096 + tid * 16);             \
    } while (0)

    const int cdiag = 2 * qt + (w >> 1);                 // wave's diagonal chunk (global idx)

    STAGE(0, cBeg * 64);
    __syncthreads();

    float mrun = -1e30f, lsum = 0.f;
    f32x16 acc0, acc1;                                   // ctx^T d-tiles 0..31 / 32..63
#pragma unroll
    for (int r = 0; r < 16; ++r) { acc0[r] = 0.f; acc1[r] = 0.f; }

    int cur = 0;
    for (int c = cBeg; c < cEnd; ++c) {
        const int kb = c * 64;
        if (c + 1 < cEnd) STAGE(cur ^ 1, kb + 64);       // overlap with compute below

        if (!(w < 2 && c == nc - 1)) {                   // w0/1: global last chunk fully masked
            const ushort* Kc = &Ksm[cur][0];
            const ushort* Vc = &Vsm[cur][0];

            // ---- QK^T: two 32x32 S-tiles (keys kb..+31, kb+32..+63); inline K reads
            f32x16 st0, st1;
#pragma unroll
            for (int r = 0; r < 16; ++r) { st0[r] = 0.f; st1[r] = 0.f; }
            __builtin_amdgcn_s_setprio(1);
#pragma unroll
            for (int dc = 0; dc < 4; ++dc) {
                short8 kf0 = *(const short8*)(Kc + l31 * 64 + (((dc * 2 + hi) ^ r7) << 3));
                short8 kf1 = *(const short8*)(Kc + (32 + l31) * 64 + (((dc * 2 + hi) ^ r7) << 3));
                st0 = MFMA32(kf0, qf[dc], st0);
                st1 = MFMA32(kf1, qf[dc], st1);
            }
            __builtin_amdgcn_s_setprio(0);

            // ---- causal mask (diagonal chunk only); key = base + (r&3) + 8*(r>>2)
            if (c == cdiag) {
                const int base0 = kb + (hi << 2);
                const int base1 = kb + 32 + (hi << 2);
#pragma unroll
                for (int r = 0; r < 16; ++r) {
                    int k0 = base0 + ((r & 3) + 8 * (r >> 2));
                    int k1 = base1 + ((r & 3) + 8 * (r >> 2));
                    st0[r] = (k0 <= qrow) ? st0[r] : -1e30f;
                    st1[r] = (k1 <= qrow) ? st1[r] : -1e30f;
                }
            }

            // ---- online softmax (log2 domain), defer-max THR=8 — tree reductions
            float tm[8];
#pragma unroll
            for (int i = 0; i < 8; ++i)
                tm[i] = fmaxf(fmaxf(st0[i], st0[i + 8]), fmaxf(st1[i], st1[i + 8]));
            float tmax = fmaxf(fmaxf(fmaxf(tm[0], tm[1]), fmaxf(tm[2], tm[3])),
                               fmaxf(fmaxf(tm[4], tm[5]), fmaxf(tm[6], tm[7])));
            tmax = fmaxf(tmax, __shfl_xor(tmax, 32));    // partner holds other half of row

            if (!__all(tmax <= mrun + 8.0f)) {
                float mnew = fmaxf(mrun, tmax);
                float sc = exp2f(mrun - mnew);
#pragma unroll
                for (int r = 0; r < 16; ++r) { acc0[r] *= sc; acc1[r] *= sc; }
                lsum *= sc;
                mrun = mnew;
            }

#pragma unroll
            for (int r = 0; r < 16; ++r) st0[r] = exp2f(st0[r] - mrun);
#pragma unroll
            for (int r = 0; r < 16; ++r) st1[r] = exp2f(st1[r] - mrun);
            float ts[8];
#pragma unroll
            for (int i = 0; i < 8; ++i) ts[i] = st0[i] + st0[i + 8];
#pragma unroll
            for (int i = 0; i < 8; ++i) ts[i] += st1[i] + st1[i + 8];
            float tsum = ((ts[0] + ts[1]) + (ts[2] + ts[3])) +
                         ((ts[4] + ts[5]) + (ts[6] + ts[7]));
            lsum += tsum;                                // partner partial merged at end

            // ---- P re-frag (select-free, r14-verified) + PV with inline V reads
#define MAKE_PFRAG(st, kcL, out)                                                        \
    do {                                                                                \
        unsigned a0 = cvtpk(st[8 * kcL + 0], st[8 * kcL + 1]);                          \
        unsigned a1 = cvtpk(st[8 * kcL + 2], st[8 * kcL + 3]);                          \
        unsigned b0 = cvtpk(st[8 * kcL + 4], st[8 * kcL + 5]);                          \
        unsigned b1 = cvtpk(st[8 * kcL + 6], st[8 * kcL + 7]);                          \
        asm volatile("v_permlane32_swap_b32 %0, %1" : "+v"(a0), "+v"(b0));              \
        asm volatile("v_permlane32_swap_b32 %0, %1" : "+v"(a1), "+v"(b1));              \
        u32x4 fw;                                                                       \
        fw.x = a0; fw.y = a1; fw.z = b0; fw.w = b1;                                     \
        out = __builtin_bit_cast(short8, fw);                                           \
    } while (0)

#define PV_GROUP(st, kcL, g)                                                            \
    do {                                                                                \
        short8 pf;                                                                      \
        MAKE_PFRAG(st, kcL, pf);                                                        \
        short8 v0 = *(const short8*)(Vc + l31 * 64 + (((2 * (g) + hi) ^ r7) << 3));     \
        short8 v1 = *(const short8*)(Vc + (32 + l31) * 64 +                             \
                                     (((2 * (g) + hi) ^ r7) << 3));                     \
        acc0 = MFMA32(v0, pf, acc0);                                                    \
        acc1 = MFMA32(v1, pf, acc1);                                                    \
    } while (0)

            __builtin_amdgcn_s_setprio(1);
            PV_GROUP(st0, 0, 0);
            PV_GROUP(st0, 1, 1);
            PV_GROUP(st1, 0, 2);
            PV_GROUP(st1, 1, 3);
            __builtin_amdgcn_s_setprio(0);
#undef PV_GROUP
#undef MAKE_PFRAG
        }

        __syncthreads();
        cur ^= 1;
    }
#undef STAGE
#undef GLL

    lsum += __shfl_xor(lsum, 32);                        // merge partner halves (row total l)

    if (SPLIT) {
        const int bid = (bh << 4) + qt;
        const int pidx = bid * 2 + half;
        const int podx = bid * 2 + (1 - half);
        // write own partials: unnormalized acc bf16 + per-row (m, l) fp32
        ushort* op = OP + (size_t)pidx * 8192 + (size_t)(w * 32 + l31) * 64;
#define WRITE_PART(accv, dt)                                                            \
    do {                                                                                \
        _Pragma("unroll")                                                               \
        for (int q2 = 0; q2 < 4; ++q2) {                                                \
            int d0 = dt * 32 + 8 * q2 + (hi << 2);                                      \
            u16x4 o;                                                                    \
            _Pragma("unroll")                                                           \
            for (int j = 0; j < 4; ++j) o[j] = f2bf(accv[4 * q2 + j]);                  \
            *(u16x4*)&op[d0] = o;                                                       \
        }                                                                               \
    } while (0)
        WRITE_PART(acc0, 0);
        WRITE_PART(acc1, 1);
#undef WRITE_PART
        if (hi == 0) {
            float2 r2 = { mrun, lsum };
            *(float2*)&ML[((size_t)pidx * 128 + w * 32 + l31) * 2] = r2;
        }
        // handshake: release own partials, claim ticket; second arriver merges.
        __threadfence();
        __syncthreads();
        if (tid == 0) sOld = atomicAdd(&FLAG[bid], 1);
        __syncthreads();
        if (sOld == 1) {
            __threadfence();                             // acquire other half's data
            const float2 mlo = *(const float2*)&ML[((size_t)podx * 128 + w * 32 + l31) * 2];
            const float M = fmaxf(mrun, mlo.x);
            const float fw_ = exp2f(mrun - M), fl_ = exp2f(mlo.x - M);
            const float inv = 1.f / (fw_ * lsum + fl_ * mlo.y);
            const ushort* opo = OP + (size_t)podx * 8192 + (size_t)(w * 32 + l31) * 64;
            const int b = bh >> 4, h = bh & 15;
            const size_t tokrow = ((size_t)b * 2048 + qw0 + l31) * 1024 + (size_t)h * 64;
#define WRITE_MERGED(accv, dt)                                                          \
    do {                                                                                \
        _Pragma("unroll")                                                               \
        for (int q2 = 0; q2 < 4; ++q2) {                                                \
            int d0 = dt * 32 + 8 * q2 + (hi << 2);                                      \
            u16x4 ao = *(const u16x4*)&opo[d0];                                         \
            u16x4 o;                                                                    \
            _Pragma("unroll")                                                           \
            for (int j = 0; j < 4; ++j)                                                 \
                o[j] = f2bf((fw_ * accv[4 * q2 + j] + fl_ * bf2f(ao[j])) * inv);        \
            *(u16x4*)&CTX[tokrow + d0] = o;                                             \
        }                                                                               \
    } while (0)
            WRITE_MERGED(acc0, 0);
            WRITE_MERGED(acc1, 1);
#undef WRITE_MERGED
        }
    } else {
        const float inv = 1.f / lsum;
        const int b = bh >> 4, h = bh & 15;
        const size_t tokrow = ((size_t)b * 2048 + qw0 + l31) * 1024 + (size_t)h * 64;
#define WRITE_DT(accv, dt)                                                              \
    do {                                                                                \
        _Pragma("unroll")                                                               \
        for (int q2 = 0; q2 < 4; ++q2) {                                                \
            int d0 = dt * 32 + 8 * q2 + (hi << 2);                                      \
            u16x4 o;                                                                    \
            _Pragma("unroll")                                                           \
            for (int j = 0; j < 4; ++j) o[j] = f2bf(accv[4 * q2 + j] * inv);            \
            *(u16x4*)&CTX[tokrow + d0] = o;                                             \
        }                                                                               \
    } while (0)
        WRITE_DT(acc0, 0);
        WRITE_DT(acc1, 1);
#undef WRITE_DT
    }
}

// ----------------------------------------------------------------------------
extern "C" void kernel_launch(void* const* d_in, const int* in_sizes, int n_in,
                              void* d_out, int out_size, void* d_ws, size_t ws_size,
                              hipStream_t stream) {
    const float* X     = (const float*)d_in[0];   // [2,2048,1024]
    const float* Wqkv  = (const float*)d_in[1];   // [1024,3072]
    const float* bqkv  = (const float*)d_in[2];   // [3072]
    const float* Wproj = (const float*)d_in[3];   // [1024,1024]
    const float* bproj = (const float*)d_in[4];   // [1024]
    float* Out = (float*)d_out;                   // [2,2048,1024] fp32

    // workspace layout (bf16 elements), base 48 MiB
    ushort* Xb     = (ushort*)d_ws;
    ushort* WqkvT  = Xb + (size_t)4096 * 1024;
    ushort* WprojT = WqkvT + (size_t)3072 * 1024;
    ushort* Qb     = WprojT + (size_t)1024 * 1024;  // [b,h,s,d] prescaled
    ushort* Kb     = Qb + (size_t)4096 * 1024;      // [b,h,s,d]
    ushort* VT     = Kb + (size_t)4096 * 1024;      // [b,h,d,s]
    ushort* CTX    = VT + (size_t)4096 * 1024;      // [tok, 1024] merged heads
    // split-K extension: OP bf16 (16 MiB) + ML fp32 (1 MiB) + FLAG (2 KiB)
    ushort* OP = (ushort*)((char*)d_ws + (size_t)48 * 1024 * 1024);
    float*  ML = (float*)(OP + (size_t)1024 * 128 * 64);
    int*  FLAG = (int*)(ML + (size_t)1024 * 128 * 2);
    const size_t NEED = (size_t)(48 + 16 + 1) * 1024 * 1024 + 4096;

    prep_kernel<<<5120, 256, 0, stream>>>(X, Xb, Wqkv, WqkvT, Wproj, WprojT);
    gemm_bt_kernel<0><<<dim3(24, 32), 256, 0, stream>>>(Xb, WqkvT, bqkv, Qb, Kb, VT, nullptr,
                                                        4096, 3072, 1024);
    if (ws_size >= NEED) {
        hipMemsetAsync(FLAG, 0, 512 * sizeof(int), stream);
        attn_kernel<1><<<1024, 256, 0, stream>>>(Qb, Kb, VT, CTX, OP, ML, FLAG);
    } else {
        attn_kernel<0><<<512, 256, 0, stream>>>(Qb, Kb, VT, CTX, nullptr, nullptr, nullptr);
    }
    gemm_bt_kernel<1><<<dim3(8, 32), 256, 0, stream>>>(CTX, WprojT, bproj, nullptr, nullptr,
                                                       nullptr, Out, 4096, 1024, 1024);
}

// Round 18
// 121.232 us; speedup vs baseline: 2.6792x; 2.6792x over previous
//
#include <hip/hip_runtime.h>
#include <hip/hip_bf16.h>

typedef __attribute__((ext_vector_type(8))) short short8;     // 8 bf16 (4 VGPRs) MFMA A/B frag
typedef __attribute__((ext_vector_type(4))) float f32x4;      // 16x16 MFMA C/D frag
typedef __attribute__((ext_vector_type(16))) float f32x16;    // 32x32 MFMA C/D frag
typedef __attribute__((ext_vector_type(4))) unsigned short u16x4;
typedef __attribute__((ext_vector_type(8))) unsigned short u16x8;
typedef __attribute__((ext_vector_type(4))) unsigned int u32x4;

#define MFMA16(a, b, c) __builtin_amdgcn_mfma_f32_16x16x32_bf16((a), (b), (c), 0, 0, 0)
#define MFMA32(a, b, c) __builtin_amdgcn_mfma_f32_32x32x16_bf16((a), (b), (c), 0, 0, 0)

__device__ __forceinline__ unsigned short f2bf(float f) {
    union { float f; unsigned u; } v; v.f = f;
    return (unsigned short)((v.u + 0x7fffu + ((v.u >> 16) & 1u)) >> 16);
}

__device__ __forceinline__ float bf2f(unsigned short s) {
    union { unsigned u; float f; } v; v.u = (unsigned)s << 16;
    return v.f;
}

__device__ __forceinline__ unsigned cvtpk(float lo, float hi_) {
    unsigned r;
    asm volatile("v_cvt_pk_bf16_f32 %0, %1, %2" : "=v"(r) : "v"(lo), "v"(hi_));
    return r;
}

// ---------------------------------------------------------------- fused prep
// blocks [0,4096): cast X f32 -> bf16 (one float4/thread)
// blocks [4096,4864): transpose+cast Wqkv [1024][3072] -> WqkvT [3072][1024]
// blocks [4864,5120): transpose+cast Wproj [1024][1024] -> WprojT [1024][1024]
__global__ __launch_bounds__(256)
void prep_kernel(const float* __restrict__ X, ushort* __restrict__ Xb,
                 const float* __restrict__ Wqkv, ushort* __restrict__ WqkvT,
                 const float* __restrict__ Wproj, ushort* __restrict__ WprojT) {
    __shared__ ushort t[64][66];                        // transpose tile (66: conflict-free)
    const int b = blockIdx.x;
    const int tid = threadIdx.x;
    if (b < 4096) {
        int i = b * 256 + tid;
        float4 v = ((const float4*)X)[i];
        u16x4 o = { f2bf(v.x), f2bf(v.y), f2bf(v.z), f2bf(v.w) };
        *(u16x4*)(Xb + (size_t)i * 4) = o;
        return;
    }
    const float* W; ushort* WT; int N, idx;
    if (b < 4864) { W = Wqkv;  WT = WqkvT;  N = 3072; idx = b - 4096; }
    else          { W = Wproj; WT = WprojT; N = 1024; idx = b - 4864; }
    const int nblk = N >> 6;
    const int n0 = (idx % nblk) * 64, k0 = (idx / nblk) * 64;
    const int tn = tid & 63, tg = tid >> 6;
#pragma unroll
    for (int i = 0; i < 16; ++i) {
        int k = tg * 16 + i;
        t[tn][k] = f2bf(W[(size_t)(k0 + k) * N + n0 + tn]);
    }
    __syncthreads();
#pragma unroll
    for (int i = 0; i < 16; ++i) {
        int nn = tg * 16 + i;
        WT[(size_t)(n0 + nn) * 1024 + k0 + tn] = t[nn][tn];
    }
}

// ---------------------------------------------------------------- GEMM C = A @ BT^T
// (round 16 — T4 counted-vmcnt 3-buffer, BK=32, slot swizzle; verified.)
#define QSCALE 0.18033688011112042f   /* 0.125 * log2(e) */

template <int MODE>
__global__ __launch_bounds__(256, 3)
void gemm_bt_kernel(const ushort* __restrict__ A, const ushort* __restrict__ BT,
                    const float* __restrict__ bias,
                    ushort* __restrict__ Qb, ushort* __restrict__ Kb,
                    ushort* __restrict__ VT, float* __restrict__ Out,
                    int M, int N, int K) {
    __shared__ ushort Asm[3][128 * 32];                 // [row][32], 16B-slot swizzled
    __shared__ ushort Bsm[3][128 * 32];
    const int tid = threadIdx.x;
    const int lane = tid & 63;
    const int wv = tid >> 6;
    const int l15 = lane & 15, lg = lane >> 4;
    const int rm = (wv >> 1) * 64, cn = (wv & 1) * 64;  // wave's 64x64 sub-tile
    const int row0 = blockIdx.y * 128, col0 = blockIdx.x * 128;

    const char* Agb = (const char*)(A + (size_t)row0 * K);
    const char* Bgb = (const char*)(BT + (size_t)col0 * K);
    const size_t rowbytes = (size_t)K * 2;

    f32x4 acc[4][4];
#pragma unroll
    for (int mi = 0; mi < 4; ++mi)
#pragma unroll
        for (int ni = 0; ni < 4; ++ni) acc[mi][ni] = f32x4{0.f, 0.f, 0.f, 0.f};

    // staging: 512 slots (128 rows x 4 x16B), 2 per thread; source col swizzled.
    const int sr0 = tid >> 2, sc0 = (tid & 3) ^ (sr0 & 3);          // slot tid
    const int sr1 = (tid + 256) >> 2, sc1 = (tid & 3) ^ (sr1 & 3);  // slot tid+256

#define GSTAGE(buf, k0_)                                                                \
    do {                                                                                \
        size_t kbyte = (size_t)(k0_)*2;                                                 \
        __builtin_amdgcn_global_load_lds(                                               \
            (const __attribute__((address_space(1))) void*)(Agb + (size_t)sr0 *         \
                rowbytes + kbyte + sc0 * 16),                                           \
            (__attribute__((address_space(3))) void*)((char*)&Asm[buf][0] + tid * 16),  \
            16, 0, 0);                                                                  \
        __builtin_amdgcn_global_load_lds(                                               \
            (const __attribute__((address_space(1))) void*)(Agb + (size_t)sr1 *         \
                rowbytes + kbyte + sc1 * 16),                                           \
            (__attribute__((address_space(3))) void*)((char*)&Asm[buf][0] + 4096 +      \
                tid * 16),                                                              \
            16, 0, 0);                                                                  \
        __builtin_amdgcn_global_load_lds(                                               \
            (const __attribute__((address_space(1))) void*)(Bgb + (size_t)sr0 *         \
                rowbytes + kbyte + sc0 * 16),                                           \
            (__attribute__((address_space(3))) void*)((char*)&Bsm[buf][0] + tid * 16),  \
            16, 0, 0);                                                                  \
        __builtin_amdgcn_global_load_lds(                                               \
            (const __attribute__((address_space(1))) void*)(Bgb + (size_t)sr1 *         \
                rowbytes + kbyte + sc1 * 16),                                           \
            (__attribute__((address_space(3))) void*)((char*)&Bsm[buf][0] + 4096 +      \
                tid * 16),                                                              \
            16, 0, 0);                                                                  \
    } while (0)

    const int NK = K >> 5;                               // 32-wide k-steps (K=1024 -> 32)
    GSTAGE(0, 0);
    GSTAGE(1, 32);

    // read swizzle: row R, elems lg*8..+7 live at slot lg^(R&3); R&3 == l15&3.
    const int sw8 = (lg ^ (l15 & 3)) << 3;

    int cur = 0, stg = 2;
    for (int i = 0; i < NK; ++i) {
        if (i < NK - 1) asm volatile("s_waitcnt vmcnt(4)" ::: "memory");
        else            asm volatile("s_waitcnt vmcnt(0)" ::: "memory");
        __builtin_amdgcn_s_barrier();                    // batch i visible; i+1 in flight
        if (i + 2 < NK) GSTAGE(stg, (i + 2) * 32);
        short8 af[4], bf[4];
#pragma unroll
        for (int mi = 0; mi < 4; ++mi)
            af[mi] = *(const short8*)&Asm[cur][(rm + mi * 16 + l15) * 32 + sw8];
#pragma unroll
        for (int ni = 0; ni < 4; ++ni)
            bf[ni] = *(const short8*)&Bsm[cur][(cn + ni * 16 + l15) * 32 + sw8];
        __builtin_amdgcn_s_setprio(1);
#pragma unroll
        for (int mi = 0; mi < 4; ++mi)
#pragma unroll
            for (int ni = 0; ni < 4; ++ni)
                acc[mi][ni] = MFMA16(af[mi], bf[ni], acc[mi][ni]);
        __builtin_amdgcn_s_setprio(0);
        cur = (cur == 2) ? 0 : cur + 1;
        stg = (stg == 2) ? 0 : stg + 1;
    }
#undef GSTAGE

    // Epilogue. D layout: lane holds D[(lg)*4+j][l15] (row=M dim, col=N dim).
    if (MODE == 0) {
        const int sect = col0 >> 10;   // 0=q 1=k 2=v, uniform per block (128 | 1024)
#pragma unroll
        for (int ni = 0; ni < 4; ++ni) {
            int col = col0 + cn + ni * 16 + l15;
            float bv = bias[col];
            int dcol = col & 1023, h = dcol >> 6, dd = dcol & 63;
#pragma unroll
            for (int mi = 0; mi < 4; ++mi) {
                int mrow0 = row0 + rm + mi * 16 + lg * 4;
                if (sect == 2) {
                    int b = mrow0 >> 11, s = mrow0 & 2047;   // 4 consecutive s, same b
                    u16x4 o;
#pragma unroll
                    for (int j = 0; j < 4; ++j) o[j] = f2bf(acc[mi][ni][j] + bv);
                    *(u16x4*)&VT[((size_t)((b << 4) + h) * 64 + dd) * 2048 + s] = o;
                } else {
                    ushort* dst = sect ? Kb : Qb;
                    float sc = sect ? 1.f : QSCALE;
#pragma unroll
                    for (int j = 0; j < 4; ++j) {
                        int tok = mrow0 + j;
                        int b = tok >> 11, s = tok & 2047;
                        dst[((size_t)((b << 4) + h) * 2048 + s) * 64 + dd] =
                            f2bf((acc[mi][ni][j] + bv) * sc);
                    }
                }
            }
        }
    } else {
#pragma unroll
        for (int ni = 0; ni < 4; ++ni) {
            int col = col0 + cn + ni * 16 + l15;
            float bv = bias[col];
#pragma unroll
            for (int mi = 0; mi < 4; ++mi) {
                int mrow0 = row0 + rm + mi * 16 + lg * 4;
#pragma unroll
                for (int j = 0; j < 4; ++j)
                    Out[(size_t)(mrow0 + j) * N + col] = acc[mi][ni][j] + bv;
            }
        }
    }
}

// ---------------------------------------------------------------- causal flash attention v12
// (round 16, verified, 46us: lean split-K, bf16 partials, NO fences/atomics —
// device-scope fences destroy per-XCD L2 residency, round-17 lesson.)
template <int SPLIT>
__global__ __launch_bounds__(256, 4)
void attn_kernel(const ushort* __restrict__ Qb, const ushort* __restrict__ Kb,
                 const ushort* __restrict__ VT, ushort* __restrict__ CTX,
                 ushort* __restrict__ OP, float* __restrict__ ML) {
    __shared__ __align__(16) ushort Ksm[2][64 * 64];    // [key][d], 16B-slot XOR-swizzled
    __shared__ __align__(16) ushort Vsm[2][64 * 64];    // [d][key], 16B-slot XOR-swizzled

    const int tid = threadIdx.x;
    const int lane = tid & 63;
    const int w = tid >> 6;
    const int l31 = lane & 31;
    const int hi = lane >> 5;                            // 0/1
    const int r7 = l31 & 7;

    const int id = blockIdx.x;
    int bh, qt, half, cBeg, cEnd;
    if (SPLIT) {
        const int xcd = id & 7, jj = id >> 3;            // jj 0..127
        bh = (xcd << 2) + (jj & 3);                      // 4 heads per XCD
        const int r = jj >> 2;                           // 0..31
        half = r >> 4;
        const int s = r & 15;
        qt = (s < 8) ? s : 23 - s;                       // orbit {r,r+8,+16,+24} -> (qt,15-qt)x2h
        cBeg = half * (qt + 1);
        cEnd = cBeg + (qt + 1);
    } else {
        const int xcd = id & 7, jj = id >> 3;
        bh = (xcd << 2) + (jj >> 4);
        qt = ((jj >> 5) & 1) ? (jj & 15) : 15 - (jj & 15);
        half = 0; cBeg = 0; cEnd = 2 * qt + 2;
    }
    const int nc = 2 * qt + 2;
    const int qw0 = qt * 128 + w * 32;                   // wave's 32 q-rows
    const int qrow = qw0 + l31;

    const ushort* Qh = Qb + (size_t)bh * 2048 * 64;
    const ushort* Kh = Kb + (size_t)bh * 2048 * 64;
    const ushort* Vh = VT + (size_t)bh * 64 * 2048;

    // Q fragments: B-operand of QK mfma: lane needs Q[qrow][dc*16+hi*8..+7]
    short8 qf[4];
#pragma unroll
    for (int dc = 0; dc < 4; ++dc)
        qf[dc] = *(const short8*)&Qh[(size_t)qrow * 64 + dc * 16 + hi * 8];

    // staging geometry (round-4-verified): LDS dest linear, global SOURCE swizzled.
    const int srow = tid >> 3;                           // 0..31
    const int sxor = ((tid & 7) ^ (srow & 7)) * 8;       // swizzled source col (elems)

#define GLL(src, dst) __builtin_amdgcn_global_load_lds(                                 \
        (const __attribute__((address_space(1))) void*)(src),                           \
        (__attribute__((address_space(3))) void*)(dst), 16, 0, 0)

#define STAGE(buf, kb_)                                                                 \
    do {                                                                                \
        const ushort* kp = Kh + (size_t)((kb_) + srow) * 64 + sxor;                     \
        GLL(kp, (char*)&Ksm[buf][0] + tid * 16);                                        \
        GLL(kp + 32 * 64, (char*)&Ksm[buf][0] + 4096 + tid * 16);                       \
        const ushort* vp = Vh + (size_t)srow * 2048 + (kb_) + sxor;                     \
        GLL(vp, (char*)&Vsm[buf][0] + tid * 16);                                        \
        GLL(vp + (size_t)32 * 2048, (char*)&Vsm[buf][0] + 4096 + tid * 16);             \
    } while (0)

    const int cdiag = 2 * qt + (w >> 1);                 // wave's diagonal chunk (global idx)

    STAGE(0, cBeg * 64);
    __syncthreads();

    float mrun = -1e30f, lsum = 0.f;
    f32x16 acc0, acc1;                                   // ctx^T d-tiles 0..31 / 32..63
#pragma unroll
    for (int r = 0; r < 16; ++r) { acc0[r] = 0.f; acc1[r] = 0.f; }

    int cur = 0;
    for (int c = cBeg; c < cEnd; ++c) {
        const int kb = c * 64;
        if (c + 1 < cEnd) STAGE(cur ^ 1, kb + 64);       // overlap with compute below

        if (!(w < 2 && c == nc - 1)) {                   // w0/1: global last chunk fully masked
            const ushort* Kc = &Ksm[cur][0];
            const ushort* Vc = &Vsm[cur][0];

            // ---- QK^T: two 32x32 S-tiles (keys kb..+31, kb+32..+63); inline K reads
            f32x16 st0, st1;
#pragma unroll
            for (int r = 0; r < 16; ++r) { st0[r] = 0.f; st1[r] = 0.f; }
            __builtin_amdgcn_s_setprio(1);
#pragma unroll
            for (int dc = 0; dc < 4; ++dc) {
                short8 kf0 = *(const short8*)(Kc + l31 * 64 + (((dc * 2 + hi) ^ r7) << 3));
                short8 kf1 = *(const short8*)(Kc + (32 + l31) * 64 + (((dc * 2 + hi) ^ r7) << 3));
                st0 = MFMA32(kf0, qf[dc], st0);
                st1 = MFMA32(kf1, qf[dc], st1);
            }
            __builtin_amdgcn_s_setprio(0);

            // ---- causal mask (diagonal chunk only); key = base + (r&3) + 8*(r>>2)
            if (c == cdiag) {
                const int base0 = kb + (hi << 2);
                const int base1 = kb + 32 + (hi << 2);
#pragma unroll
                for (int r = 0; r < 16; ++r) {
                    int k0 = base0 + ((r & 3) + 8 * (r >> 2));
                    int k1 = base1 + ((r & 3) + 8 * (r >> 2));
                    st0[r] = (k0 <= qrow) ? st0[r] : -1e30f;
                    st1[r] = (k1 <= qrow) ? st1[r] : -1e30f;
                }
            }

            // ---- online softmax (log2 domain), defer-max THR=8 — tree reductions
            float tm[8];
#pragma unroll
            for (int i = 0; i < 8; ++i)
                tm[i] = fmaxf(fmaxf(st0[i], st0[i + 8]), fmaxf(st1[i], st1[i + 8]));
            float tmax = fmaxf(fmaxf(fmaxf(tm[0], tm[1]), fmaxf(tm[2], tm[3])),
                               fmaxf(fmaxf(tm[4], tm[5]), fmaxf(tm[6], tm[7])));
            tmax = fmaxf(tmax, __shfl_xor(tmax, 32));    // partner holds other half of row

            if (!__all(tmax <= mrun + 8.0f)) {
                float mnew = fmaxf(mrun, tmax);
                float sc = exp2f(mrun - mnew);
#pragma unroll
                for (int r = 0; r < 16; ++r) { acc0[r] *= sc; acc1[r] *= sc; }
                lsum *= sc;
                mrun = mnew;
            }

#pragma unroll
            for (int r = 0; r < 16; ++r) st0[r] = exp2f(st0[r] - mrun);
#pragma unroll
            for (int r = 0; r < 16; ++r) st1[r] = exp2f(st1[r] - mrun);
            float ts[8];
#pragma unroll
            for (int i = 0; i < 8; ++i) ts[i] = st0[i] + st0[i + 8];
#pragma unroll
            for (int i = 0; i < 8; ++i) ts[i] += st1[i] + st1[i + 8];
            float tsum = ((ts[0] + ts[1]) + (ts[2] + ts[3])) +
                         ((ts[4] + ts[5]) + (ts[6] + ts[7]));
            lsum += tsum;                                // partner partial merged at end

            // ---- P re-frag (select-free, r14-verified) + PV with inline V reads
#define MAKE_PFRAG(st, kcL, out)                                                        \
    do {                                                                                \
        unsigned a0 = cvtpk(st[8 * kcL + 0], st[8 * kcL + 1]);                          \
        unsigned a1 = cvtpk(st[8 * kcL + 2], st[8 * kcL + 3]);                          \
        unsigned b0 = cvtpk(st[8 * kcL + 4], st[8 * kcL + 5]);                          \
        unsigned b1 = cvtpk(st[8 * kcL + 6], st[8 * kcL + 7]);                          \
        asm volatile("v_permlane32_swap_b32 %0, %1" : "+v"(a0), "+v"(b0));              \
        asm volatile("v_permlane32_swap_b32 %0, %1" : "+v"(a1), "+v"(b1));              \
        u32x4 fw;                                                                       \
        fw.x = a0; fw.y = a1; fw.z = b0; fw.w = b1;                                     \
        out = __builtin_bit_cast(short8, fw);                                           \
    } while (0)

#define PV_GROUP(st, kcL, g)                                                            \
    do {                                                                                \
        short8 pf;                                                                      \
        MAKE_PFRAG(st, kcL, pf);                                                        \
        short8 v0 = *(const short8*)(Vc + l31 * 64 + (((2 * (g) + hi) ^ r7) << 3));     \
        short8 v1 = *(const short8*)(Vc + (32 + l31) * 64 +                             \
                                     (((2 * (g) + hi) ^ r7) << 3));                     \
        acc0 = MFMA32(v0, pf, acc0);                                                    \
        acc1 = MFMA32(v1, pf, acc1);                                                    \
    } while (0)

            __builtin_amdgcn_s_setprio(1);
            PV_GROUP(st0, 0, 0);
            PV_GROUP(st0, 1, 1);
            PV_GROUP(st1, 0, 2);
            PV_GROUP(st1, 1, 3);
            __builtin_amdgcn_s_setprio(0);
#undef PV_GROUP
#undef MAKE_PFRAG
        }

        __syncthreads();
        cur ^= 1;
    }
#undef STAGE
#undef GLL

    lsum += __shfl_xor(lsum, 32);                        // merge partner halves (row total l)

    if (SPLIT) {
        // partial write: unnormalized acc in BF16 + per-row (m, l) fp32
        const int pidx = ((bh << 4) + qt) * 2 + half;
        ushort* op = OP + (size_t)pidx * 8192 + (size_t)(w * 32 + l31) * 64;
#define WRITE_PART(accv, dt)                                                            \
    do {                                                                                \
        _Pragma("unroll")                                                               \
        for (int q2 = 0; q2 < 4; ++q2) {                                                \
            int d0 = dt * 32 + 8 * q2 + (hi << 2);                                      \
            u16x4 o;                                                                    \
            _Pragma("unroll")                                                           \
            for (int j = 0; j < 4; ++j) o[j] = f2bf(accv[4 * q2 + j]);                  \
            *(u16x4*)&op[d0] = o;                                                       \
        }                                                                               \
    } while (0)
        WRITE_PART(acc0, 0);
        WRITE_PART(acc1, 1);
#undef WRITE_PART
        if (hi == 0) {
            float2 r2 = { mrun, lsum };
            *(float2*)&ML[((size_t)pidx * 128 + w * 32 + l31) * 2] = r2;
        }
    } else {
        const float inv = 1.f / lsum;
        const int b = bh >> 4, h = bh & 15;
        const size_t tokrow = ((size_t)b * 2048 + qw0 + l31) * 1024 + (size_t)h * 64;
#define WRITE_DT(accv, dt)                                                              \
    do {                                                                                \
        _Pragma("unroll")                                                               \
        for (int q2 = 0; q2 < 4; ++q2) {                                                \
            int d0 = dt * 32 + 8 * q2 + (hi << 2);                                      \
            u16x4 o;                                                                    \
            _Pragma("unroll")                                                           \
            for (int j = 0; j < 4; ++j) o[j] = f2bf(accv[4 * q2 + j] * inv);            \
            *(u16x4*)&CTX[tokrow + d0] = o;                                             \
        }                                                                               \
    } while (0)
        WRITE_DT(acc0, 0);
        WRITE_DT(acc1, 1);
#undef WRITE_DT
    }
}

// ---------------------------------------------------------------- split-K merge
// out = (f0*A0 + f1*A1) / (f0*l0 + f1*l1), f_h = exp2(m_h - max(m0,m1)).
// Fully coalesced: thread handles flat groups g = tid + it*256 of 8 bf16.
__global__ __launch_bounds__(256)
void merge_kernel(const ushort* __restrict__ OP, const float* __restrict__ ML,
                  ushort* __restrict__ CTX) {
    const int bid = blockIdx.x;                          // bh*16 + qt
    const int bh = bid >> 4, qt = bid & 15;
    const int tid = threadIdx.x;
    const size_t base0 = (size_t)(bid * 2) * 8192;
    const size_t mlb = (size_t)(bid * 2) * 128;
#pragma unroll
    for (int it = 0; it < 4; ++it) {
        const int g = tid + it * 256;                    // 0..1023
        const int row = g >> 3, d0 = (g & 7) * 8;        // row*64+d0 == g*8
        const float2 ml0 = *(const float2*)&ML[(mlb + row) * 2];
        const float2 ml1 = *(const float2*)&ML[(mlb + 128 + row) * 2];
        const float M = fmaxf(ml0.x, ml1.x);
        const float f0 = exp2f(ml0.x - M), f1 = exp2f(ml1.x - M);
        const float inv = 1.f / (f0 * ml0.y + f1 * ml1.y);
        const u16x8 a0 = *(const u16x8*)&OP[base0 + (size_t)g * 8];
        const u16x8 a1 = *(const u16x8*)&OP[base0 + 8192 + (size_t)g * 8];
        u16x8 o;
#pragma unroll
        for (int j = 0; j < 8; ++j)
            o[j] = f2bf((f0 * bf2f(a0[j]) + f1 * bf2f(a1[j])) * inv);
        const size_t tok = (size_t)(bh >> 4) * 2048 + qt * 128 + row;
        *(u16x8*)&CTX[tok * 1024 + (size_t)(bh & 15) * 64 + d0] = o;
    }
}

// ----------------------------------------------------------------------------
extern "C" void kernel_launch(void* const* d_in, const int* in_sizes, int n_in,
                              void* d_out, int out_size, void* d_ws, size_t ws_size,
                              hipStream_t stream) {
    const float* X     = (const float*)d_in[0];   // [2,2048,1024]
    const float* Wqkv  = (const float*)d_in[1];   // [1024,3072]
    const float* bqkv  = (const float*)d_in[2];   // [3072]
    const float* Wproj = (const float*)d_in[3];   // [1024,1024]
    const float* bproj = (const float*)d_in[4];   // [1024]
    float* Out = (float*)d_out;                   // [2,2048,1024] fp32

    // workspace layout (bf16 elements), base 48 MiB
    ushort* Xb     = (ushort*)d_ws;
    ushort* WqkvT  = Xb + (size_t)4096 * 1024;
    ushort* WprojT = WqkvT + (size_t)3072 * 1024;
    ushort* Qb     = WprojT + (size_t)1024 * 1024;  // [b,h,s,d] prescaled
    ushort* Kb     = Qb + (size_t)4096 * 1024;      // [b,h,s,d]
    ushort* VT     = Kb + (size_t)4096 * 1024;      // [b,h,d,s]
    ushort* CTX    = VT + (size_t)4096 * 1024;      // [tok, 1024] merged heads
    // split-K extension: OP bf16 (16 MiB) + ML fp32 (1 MiB)
    ushort* OP = (ushort*)((char*)d_ws + (size_t)48 * 1024 * 1024);
    float*  ML = (float*)(OP + (size_t)1024 * 128 * 64);
    const size_t NEED = (size_t)(48 + 16 + 1) * 1024 * 1024;

    prep_kernel<<<5120, 256, 0, stream>>>(X, Xb, Wqkv, WqkvT, Wproj, WprojT);
    gemm_bt_kernel<0><<<dim3(24, 32), 256, 0, stream>>>(Xb, WqkvT, bqkv, Qb, Kb, VT, nullptr,
                                                        4096, 3072, 1024);
    if (ws_size >= NEED) {
        attn_kernel<1><<<1024, 256, 0, stream>>>(Qb, Kb, VT, CTX, OP, ML);
        merge_kernel<<<512, 256, 0, stream>>>(OP, ML, CTX);
    } else {
        attn_kernel<0><<<512, 256, 0, stream>>>(Qb, Kb, VT, CTX, nullptr, nullptr);
    }
    gemm_bt_kernel<1><<<dim3(8, 32), 256, 0, stream>>>(CTX, WprojT, bproj, nullptr, nullptr,
                                                       nullptr, Out, 4096, 1024, 1024);
}